// Round 10
// baseline (215.759 us; speedup 1.0000x reference)
//
#include <hip/hip_runtime.h>
#include <stdint.h>

typedef short short8 __attribute__((ext_vector_type(8)));
typedef short short4v __attribute__((ext_vector_type(4)));
typedef float f32x4 __attribute__((ext_vector_type(4)));
typedef float float4v __attribute__((ext_vector_type(4)));

__device__ inline float bf2f(short s) {
    union { unsigned u; float f; } c;
    c.u = ((unsigned)(unsigned short)s) << 16;
    return c.f;
}
__device__ inline short f2bf(float f) {
    union { float f; unsigned u; } c;
    c.f = f;
    unsigned u = c.u;
    unsigned r = (u + 0x7fffu + ((u >> 16) & 1u)) >> 16;
    return (short)r;
}

typedef const __attribute__((address_space(1))) char GChar;
typedef __attribute__((address_space(3))) char LChar;
__device__ __forceinline__ void gload_lds16(const void* g, void* l) {
    __builtin_amdgcn_global_load_lds((GChar*)g, (LChar*)l, 16, 0, 0);
}

template<int N> __device__ __forceinline__ void wait_vm() {
    if constexpr (N == 0)      asm volatile("s_waitcnt vmcnt(0)" ::: "memory");
    else if constexpr (N == 6) asm volatile("s_waitcnt vmcnt(6)" ::: "memory");
    else static_assert(N == 0 || N == 6, "unsupported vmcnt");
}

__device__ __forceinline__ void phase_barrier() {
    __builtin_amdgcn_s_barrier();
    asm volatile("" ::: "memory");
}

// XCD-aware (x,y)-plane swizzle; requires gridDim.x*gridDim.y % 8 == 0.
__device__ __forceinline__ void swz_xy(int& bx, int& by) {
    int gx = gridDim.x;
    int nwg = gx * gridDim.y;
    int wg = by * gx + bx;
    int chunk = nwg >> 3;
    int swz = (wg & 7) * chunk + (wg >> 3);
    bx = swz % gx;
    by = swz / gx;
}

// ---------------- all-4 weight fp32 -> bf16 convert (wq scaled) ----------------
__global__ __launch_bounds__(256) void conv_w4(const float* __restrict__ w0, const float* __restrict__ w1,
                                               const float* __restrict__ w2, const float* __restrict__ w3,
                                               short* __restrict__ dst, float s0) {
    int idx = (blockIdx.x * 256 + threadIdx.x) * 4;
    int wi = idx >> 18;
    int off = idx & 262143;
    const float* src = (wi == 0) ? w0 : (wi == 1) ? w1 : (wi == 2) ? w2 : w3;
    float sc = (wi == 0) ? s0 : 1.0f;
    float4v v = *reinterpret_cast<const float4v*>(src + off);
    short4v o;
    o[0] = f2bf(v[0] * sc); o[1] = f2bf(v[1] * sc);
    o[2] = f2bf(v[2] * sc); o[3] = f2bf(v[3] * sc);
    *reinterpret_cast<short4v*>(dst + idx) = o;
}

// bqk[0:512] = bq*s ; bqk[512:1024] = bk
__global__ __launch_bounds__(256) void prep_bias(const float* __restrict__ bq, const float* __restrict__ bk,
                                                 float* __restrict__ bqk, float s) {
    int i = blockIdx.x * 256 + threadIdx.x;
    bqk[i] = (i < 512) ? bq[i] * s : bk[i - 512];
}

// ---------------- GroupNorm stats: one block per (b,g) ----------------
__global__ __launch_bounds__(256) void gn_stats(const float* __restrict__ x, float* __restrict__ stats) {
    int bg = blockIdx.x;
    const float* p = x + (size_t)bg * (16 * 4096);
    float s = 0.f, ss = 0.f;
    for (int i = threadIdx.x * 4; i < 65536; i += 1024) {
        float4v q = *reinterpret_cast<const float4v*>(p + i);
        s  += q[0] + q[1] + q[2] + q[3];
        ss += q[0]*q[0] + q[1]*q[1] + q[2]*q[2] + q[3]*q[3];
    }
    #pragma unroll
    for (int off = 32; off >= 1; off >>= 1) {
        s  += __shfl_xor(s, off);
        ss += __shfl_xor(ss, off);
    }
    __shared__ float rs[8];
    int w = threadIdx.x >> 6, lane = threadIdx.x & 63;
    if (lane == 0) { rs[w] = s; rs[4 + w] = ss; }
    __syncthreads();
    if (threadIdx.x == 0) {
        float S1 = rs[0] + rs[1] + rs[2] + rs[3];
        float S2 = rs[4] + rs[5] + rs[6] + rs[7];
        float mean = S1 * (1.f / 65536.f);
        float var  = S2 * (1.f / 65536.f) - mean * mean;
        stats[bg * 2]     = mean;
        stats[bg * 2 + 1] = rsqrtf(var + 1e-6f);
    }
}

// ---------------- GN apply + transpose: x[b][c][n] -> hT[b][n][c] (bf16) ----------------
__global__ __launch_bounds__(256) void gn_apply_t(const float* __restrict__ x, const float* __restrict__ stats,
                                                  const float* __restrict__ scale, const float* __restrict__ bias,
                                                  short* __restrict__ hT) {
    __shared__ float t[64][65];
    int n0 = blockIdx.x * 64, c0 = blockIdx.y * 64, b = blockIdx.z;
    const float* xb = x + (size_t)b * 512 * 4096;
    int col = threadIdx.x & 63, rb = threadIdx.x >> 6;
    #pragma unroll
    for (int r = 0; r < 16; ++r) {
        int cl = rb + r * 4;
        int c = c0 + cl;
        int g = c >> 4;
        float mean = stats[(b * 32 + g) * 2];
        float rstd = stats[(b * 32 + g) * 2 + 1];
        float v = xb[(size_t)c * 4096 + n0 + col];
        t[col][cl] = (v - mean) * rstd * scale[c] + bias[c];
    }
    __syncthreads();
    short* hb = hT + (size_t)b * 4096 * 512;
    #pragma unroll
    for (int r = 0; r < 16; ++r) {
        int nl = rb + r * 4;
        hb[(size_t)(n0 + nl) * 512 + c0 + col] = f2bf(t[nl][col]);
    }
}

// ================ 256x128 NT GEMM, BK=32, 3-buffer, 2 blocks/CU ================
// C[M][N] = A[M][K]*B[N][K]^T, bf16 in, fp32 acc, bf16 out. 512 threads = 8 waves
// (4M x 2N), wave output 64x64 (acc = 64 VGPR). LDS 3 x 24KB = 72KB -> 2 blocks/CU
// (16 waves/CU): inter-block overlap hides stalls (m97/m114 mechanism).
// Loop: {vmcnt(0) [distance-2 prefetch => usually landed]; barrier; stage(t+2);
// read 8 frags; 16 MFMA}. Race-free: stage-after-barrier, buffer (t+2)%3 was
// last read at iter t-1, all waves past barrier. 64B LDS rows, swizzle
// (kk*16)^((r&3)<<4) -> 8 lanes/16B-slot uniform (structural minimum, 0 conflicts).
__global__ __launch_bounds__(512, 4) void gemm_bk32(
    const short* __restrict__ A, int zdiv, long sAb1, long sAb2, int lda,
    const short* __restrict__ B, long sBb1, long sBb2, int ldb,
    short* __restrict__ C, long sCb1, long sCb2, int ldc,
    int K, const float* __restrict__ bias)
{
    __shared__ __align__(16) char lds[73728];   // 3 buf x (A 16KB + B 8KB)

    const int tid = threadIdx.x;
    int bx = blockIdx.x, by = blockIdx.y;
    swz_xy(bx, by);
    const int bm = bx * 256, bn = by * 128;
    const int zb = blockIdx.z / zdiv, zs = blockIdx.z % zdiv;

    const short* Ab = A + (size_t)zb * sAb1 + (size_t)zs * sAb2;
    const short* Bb = B + (size_t)zb * sBb1 + (size_t)zs * sBb2;

    const int w = tid >> 6, lane = tid & 63;
    const int wm = w >> 1, wn = w & 1;          // 4M x 2N
    const int l15 = lane & 15, l4 = lane >> 4;

    // staging: A = 1024 chunks (2/thread), B = 512 chunks (1/thread).
    // chunk ch: r = ch>>2, c = ch&3 ; src col = (c ^ (r&3))*8 elems ; dst = r*64 + c*16
    long srcA0, srcA1, srcB0; int dstA0, dstA1, dstB0;
    { int ch = tid;       int r = ch >> 2, c = ch & 3;
      srcA0 = (long)(bm + r) * lda + ((c ^ (r & 3)) << 3); dstA0 = r * 64 + c * 16; }
    { int ch = tid + 512; int r = ch >> 2, c = ch & 3;
      srcA1 = (long)(bm + r) * lda + ((c ^ (r & 3)) << 3); dstA1 = r * 64 + c * 16; }
    { int ch = tid;       int r = ch >> 2, c = ch & 3;
      srcB0 = (long)(bn + r) * ldb + ((c ^ (r & 3)) << 3); dstB0 = 16384 + r * 64 + c * 16; }

    auto stage = [&](int buf, long kt) {
        char* l = lds + buf * 24576;
        gload_lds16(Ab + srcA0 + kt, l + dstA0);
        gload_lds16(Ab + srcA1 + kt, l + dstA1);
        gload_lds16(Bb + srcB0 + kt, l + dstB0);
    };

    f32x4 acc[4][4] = {};
    const int nk = K >> 5;

    stage(0, 0);
    if (nk > 1) stage(1, 32);

    for (int t = 0; t < nk; ++t) {
        wait_vm<0>();              // t's loads landed (issued 2 iters ago) — cheap
        phase_barrier();           // cross-wave: everyone's loads landed; prev reads done
        if (t + 2 < nk) stage((t + 2) % 3, (long)(t + 2) << 5);

        const char* l = lds + (t % 3) * 24576;
        short8 af[4], bfv[4];
        #pragma unroll
        for (int m = 0; m < 4; ++m) {
            int r = wm * 64 + m * 16 + l15;
            af[m] = *reinterpret_cast<const short8*>(l + r * 64 + ((l4 * 16) ^ ((r & 3) << 4)));
        }
        #pragma unroll
        for (int n = 0; n < 4; ++n) {
            int r = wn * 64 + n * 16 + l15;
            bfv[n] = *reinterpret_cast<const short8*>(l + 16384 + r * 64 + ((l4 * 16) ^ ((r & 3) << 4)));
        }
        __builtin_amdgcn_s_setprio(1);
        #pragma unroll
        for (int m = 0; m < 4; ++m)
            #pragma unroll
            for (int n = 0; n < 4; ++n)
                acc[m][n] = __builtin_amdgcn_mfma_f32_16x16x32_bf16(af[m], bfv[n], acc[m][n], 0, 0, 0);
        __builtin_amdgcn_s_setprio(0);
    }

    short* Cb = C + (size_t)zb * sCb1 + (size_t)zs * sCb2;
    #pragma unroll
    for (int n = 0; n < 4; ++n) {
        int col = bn + wn * 64 + n * 16 + l15;
        float bv = bias ? bias[col] : 0.0f;
        #pragma unroll
        for (int m = 0; m < 4; ++m) {
            #pragma unroll
            for (int r = 0; r < 4; ++r) {
                int row = bm + wm * 64 + m * 16 + l4 * 4 + r;
                Cb[(size_t)row * ldc + col] = f2bf(acc[m][n][r] + bv);
            }
        }
    }
}

// ---------------- small NT GEMM (4 waves, 128 x BNT), counted-vmcnt pipeline ----------------
template<int BNT>
__global__ __launch_bounds__(256) void gemm_nt2(
    const short* __restrict__ A, long sAb, int lda,
    const short* __restrict__ B, long sBb, int ldb,
    void* __restrict__ Cv, long sCb, int ldc,
    int K,
    const float* __restrict__ bias, int bias_mode,
    const float* __restrict__ res, long sResb,
    int c_fp32)
{
    constexpr int BMT = 128;
    constexpr int NF  = BNT / 32;
    constexpr int BUF = (BMT + BNT) * 128;
    constexpr int ALPT = (BMT * 8) / 256;
    constexpr int BLPT = (BNT * 8) / 256;
    constexpr int LPT  = ALPT + BLPT;
    __shared__ __align__(16) char lds[2 * BUF];

    const int tid = threadIdx.x;
    int bx = blockIdx.x, by = blockIdx.y;
    swz_xy(bx, by);
    const int bm = bx * BMT;
    const int bn = by * BNT;
    const int bz = blockIdx.z;

    const short* Ab = A + (size_t)bz * sAb;
    const short* Bb = B + (size_t)bz * sBb;

    const int w = tid >> 6;
    const int lane = tid & 63;
    const int wr = (w >> 1) * 64;
    const int wc = (w & 1) * (BNT / 2);

    f32x4 acc[4][NF] = {};
    const int nk = K >> 6;

    auto stage = [&](int buf, int kt) {
        char* la = lds + buf * BUF;
        char* lb = la + BMT * 128;
        #pragma unroll
        for (int i = 0; i < ALPT; ++i) {
            int ch = i * 256 + tid;
            int r = ch >> 3, c = ch & 7;
            gload_lds16(Ab + (size_t)(bm + r) * lda + kt + ((c ^ (r & 7)) << 3), la + ch * 16);
        }
        #pragma unroll
        for (int i = 0; i < BLPT; ++i) {
            int ch = i * 256 + tid;
            int r = ch >> 3, c = ch & 7;
            gload_lds16(Bb + (size_t)(bn + r) * ldb + kt + ((c ^ (r & 7)) << 3), lb + ch * 16);
        }
    };

    stage(0, 0);
    int cur = 0;
    for (int t = 0; t < nk; ++t) {
        if (t + 1 < nk) {
            stage(cur ^ 1, (t + 1) << 6);
            wait_vm<6>();
        } else {
            wait_vm<0>();
        }
        phase_barrier();

        const char* la = lds + cur * BUF;
        const char* lb = la + BMT * 128;
        #pragma unroll
        for (int ks = 0; ks < 2; ++ks) {
            const int kb = ks * 64 + (lane >> 4) * 16;
            short8 af[4], bfv[NF];
            #pragma unroll
            for (int m = 0; m < 4; ++m) {
                int r = wr + m * 16 + (lane & 15);
                af[m] = *reinterpret_cast<const short8*>(la + r * 128 + (kb ^ ((r & 7) << 4)));
            }
            #pragma unroll
            for (int n = 0; n < NF; ++n) {
                int r = wc + n * 16 + (lane & 15);
                bfv[n] = *reinterpret_cast<const short8*>(lb + r * 128 + (kb ^ ((r & 7) << 4)));
            }
            #pragma unroll
            for (int m = 0; m < 4; ++m)
                #pragma unroll
                for (int n = 0; n < NF; ++n)
                    acc[m][n] = __builtin_amdgcn_mfma_f32_16x16x32_bf16(af[m], bfv[n], acc[m][n], 0, 0, 0);
        }
        asm volatile("" ::: "memory");
        __builtin_amdgcn_s_barrier();
        cur ^= 1;
    }

    const int row0 = (lane >> 4) * 4;
    const int col0 = lane & 15;
    short* Cb16 = (short*)Cv + (size_t)bz * sCb;
    float* Cf32 = (float*)Cv + (size_t)bz * sCb;
    const float* resb = res ? res + (size_t)bz * sResb : nullptr;

    #pragma unroll
    for (int m = 0; m < 4; ++m) {
        #pragma unroll
        for (int r = 0; r < 4; ++r) {
            int row = bm + wr + m * 16 + row0 + r;
            float bvr = (bias_mode == 1) ? bias[row] : 0.0f;
            #pragma unroll
            for (int n = 0; n < NF; ++n) {
                int col = bn + wc + n * 16 + col0;
                float v = acc[m][n][r];
                if (bias_mode == 1) v += bvr;
                else if (bias_mode == 2) v += bias[col];
                size_t idx = (size_t)row * ldc + col;
                if (c_fp32) {
                    if (resb) v += resb[idx];
                    Cf32[idx] = v;
                } else {
                    Cb16[idx] = f2bf(v);
                }
            }
        }
    }
}

// ---------------- row softmax in-place on bf16 [4096] rows (both batches) ----------------
__global__ __launch_bounds__(256) void softmax_rows(short* __restrict__ S) {
    const int N = 4096;
    short* p = S + (size_t)blockIdx.x * N + threadIdx.x * 16;
    short8 r0 = *reinterpret_cast<short8*>(p);
    short8 r1 = *reinterpret_cast<short8*>(p + 8);
    float v[16];
    #pragma unroll
    for (int i = 0; i < 8; ++i) { v[i] = bf2f(r0[i]); v[8 + i] = bf2f(r1[i]); }
    float mx = v[0];
    #pragma unroll
    for (int i = 1; i < 16; ++i) mx = fmaxf(mx, v[i]);
    #pragma unroll
    for (int off = 32; off >= 1; off >>= 1) mx = fmaxf(mx, __shfl_xor(mx, off));
    __shared__ float red[8];
    int w = threadIdx.x >> 6, lane = threadIdx.x & 63;
    if (lane == 0) red[w] = mx;
    __syncthreads();
    mx = fmaxf(fmaxf(red[0], red[1]), fmaxf(red[2], red[3]));
    float s = 0.f;
    #pragma unroll
    for (int i = 0; i < 16; ++i) { v[i] = __expf(v[i] - mx); s += v[i]; }
    #pragma unroll
    for (int off = 32; off >= 1; off >>= 1) s += __shfl_xor(s, off);
    if (lane == 0) red[4 + w] = s;
    __syncthreads();
    s = (red[4] + red[5]) + (red[6] + red[7]);
    float inv = 1.0f / s;
    #pragma unroll
    for (int i = 0; i < 8; ++i) { r0[i] = f2bf(v[i] * inv); r1[i] = f2bf(v[8 + i] * inv); }
    *reinterpret_cast<short8*>(p) = r0;
    *reinterpret_cast<short8*>(p + 8) = r1;
}

// ---------------- split-K reduce: OT_bf16 = sum of 4 bf16 partials (grid.y = batch) ----------------
__global__ __launch_bounds__(256) void reduce4b(const short* __restrict__ p, short* __restrict__ o) {
    const long NN = 4096L * 512L;
    const short* pb = p + (size_t)blockIdx.y * 4 * NN;
    short* ob = o + (size_t)blockIdx.y * NN;
    long i = (blockIdx.x * 256 + threadIdx.x) * 8L;
    short8 a = *reinterpret_cast<const short8*>(pb + i);
    short8 b = *reinterpret_cast<const short8*>(pb + NN + i);
    short8 c = *reinterpret_cast<const short8*>(pb + 2 * NN + i);
    short8 d = *reinterpret_cast<const short8*>(pb + 3 * NN + i);
    short8 r;
    #pragma unroll
    for (int j = 0; j < 8; ++j)
        r[j] = f2bf((bf2f(a[j]) + bf2f(b[j])) + (bf2f(c[j]) + bf2f(d[j])));
    *reinterpret_cast<short8*>(ob + i) = r;
}

extern "C" void kernel_launch(void* const* d_in, const int* in_sizes, int n_in,
                              void* d_out, int out_size, void* d_ws, size_t ws_size,
                              hipStream_t stream) {
    (void)in_sizes; (void)n_in; (void)out_size; (void)ws_size;
    const float* x        = (const float*)d_in[0];
    const float* gn_scale = (const float*)d_in[1];
    const float* gn_bias  = (const float*)d_in[2];
    const float* wq = (const float*)d_in[3];
    const float* bq = (const float*)d_in[4];
    const float* wk = (const float*)d_in[5];
    const float* bk = (const float*)d_in[6];
    const float* wv = (const float*)d_in[7];
    const float* bv = (const float*)d_in[8];
    const float* wp = (const float*)d_in[9];
    const float* bp = (const float*)d_in[10];

    char* ws = (char*)d_ws;
    const size_t MB = 1024 * 1024;
    short* hT   = (short*)(ws + 0);         // [2][4096][512] bf16     (8MB)
    short* QKT  = (short*)(ws + 8   * MB);  // [2][4096][1024] bf16   (16MB)
    short* V    = (short*)(ws + 24  * MB);  // [2][512][4096] bf16     (8MB)
    short* OT   = (short*)(ws + 32  * MB);  // [2][4096][512] bf16     (8MB)
    short* S    = (short*)(ws + 40  * MB);  // [2][4096][4096] bf16   (64MB)
    short* part = (short*)(ws + 104 * MB);  // [2][4][4096][512] bf16 (32MB)
    short* wB   = (short*)(ws + 168 * MB);  // wq,wk,wv,wp bf16        (2MB)
    float* stats= (float*)(ws + 170 * MB);  // 128 f
    float* bqk  = (float*)(ws + 170 * MB + 4096);  // 1024 f

    const long NC   = 4096L * 512L;    // 2M
    const long CN   = 512L * 4096L;
    const long QKNC = 4096L * 1024L;   // 4M
    const long SNN  = 4096L * 4096L;   // 16M
    const float attn_scale = 0.044194173824159216f;  // 512^-0.5

    conv_w4<<<1024, 256, 0, stream>>>(wq, wk, wv, wp, wB, attn_scale);
    prep_bias<<<4, 256, 0, stream>>>(bq, bk, bqk, attn_scale);

    gn_stats<<<64, 256, 0, stream>>>(x, stats);
    gn_apply_t<<<dim3(64, 8, 2), 256, 0, stream>>>(x, stats, gn_scale, gn_bias, hT);

    // QK projection (merged): QKT[b][n][0:512]=Q*s, [512:1024]=K
    gemm_bk32<<<dim3(16, 8, 2), 512, 0, stream>>>(
        hT, 1, NC, 0, 512, wB, 0, 0, 512, QKT, QKNC, 0, 1024, 512, bqk);
    // V[b][c][n]
    gemm_nt2<64><<<dim3(4, 64, 2), 256, 0, stream>>>(
        wB + 524288, 0, 512, hT, NC, 512, V, CN, 4096, 512, bv, 1, nullptr, 0, 0);

    // S[b][i][j] = sum_c Q[i][c] K[j][c]  (scale pre-folded), both batches
    gemm_bk32<<<dim3(16, 32, 2), 512, 0, stream>>>(
        QKT, 1, QKNC, 0, 1024, QKT + 512, QKNC, 0, 1024, S, SNN, 0, 4096, 512, nullptr);
    softmax_rows<<<8192, 256, 0, stream>>>(S);
    // PV split-K=4, both batches: z = batch*4 + slice, K=1024 per slice, bf16 partials
    gemm_bk32<<<dim3(16, 4, 8), 512, 0, stream>>>(
        S, 4, SNN, 1024, 4096, V, CN, 1024, 4096, part, 4L * NC, NC, 512, 1024, nullptr);
    reduce4b<<<dim3(1024, 2), 256, 0, stream>>>(part, OT);

    // out[b][c][n] = wp . o + bp + x
    gemm_nt2<64><<<dim3(4, 64, 2), 256, 0, stream>>>(
        wB + 786432, 0, 512, OT, NC, 512, d_out, CN, 4096, 512, bp, 1, x, CN, 1);
}

// Round 11
// 199.633 us; speedup vs baseline: 1.0808x; 1.0808x over previous
//
#include <hip/hip_runtime.h>
#include <stdint.h>

typedef short short8 __attribute__((ext_vector_type(8)));
typedef short short4v __attribute__((ext_vector_type(4)));
typedef float f32x4 __attribute__((ext_vector_type(4)));
typedef float float4v __attribute__((ext_vector_type(4)));

__device__ inline float bf2f(short s) {
    union { unsigned u; float f; } c;
    c.u = ((unsigned)(unsigned short)s) << 16;
    return c.f;
}
__device__ inline short f2bf(float f) {
    union { float f; unsigned u; } c;
    c.f = f;
    unsigned u = c.u;
    unsigned r = (u + 0x7fffu + ((u >> 16) & 1u)) >> 16;
    return (short)r;
}

typedef const __attribute__((address_space(1))) char GChar;
typedef __attribute__((address_space(3))) char LChar;
__device__ __forceinline__ void gload_lds16(const void* g, void* l) {
    __builtin_amdgcn_global_load_lds((GChar*)g, (LChar*)l, 16, 0, 0);
}

template<int N> __device__ __forceinline__ void wait_vm() {
    if constexpr (N == 0)      asm volatile("s_waitcnt vmcnt(0)" ::: "memory");
    else if constexpr (N == 4) asm volatile("s_waitcnt vmcnt(4)" ::: "memory");
    else if constexpr (N == 6) asm volatile("s_waitcnt vmcnt(6)" ::: "memory");
    else static_assert(N == 0 || N == 4 || N == 6, "unsupported vmcnt");
}

__device__ __forceinline__ void phase_barrier() {
    __builtin_amdgcn_s_barrier();
    asm volatile("" ::: "memory");
}

// XCD-aware (x,y)-plane swizzle; requires gridDim.x*gridDim.y % 8 == 0.
__device__ __forceinline__ void swz_xy(int& bx, int& by) {
    int gx = gridDim.x;
    int nwg = gx * gridDim.y;
    int wg = by * gx + bx;
    int chunk = nwg >> 3;
    int swz = (wg & 7) * chunk + (wg >> 3);
    bx = swz % gx;
    by = swz / gx;
}

// ---------------- all-4 weight fp32 -> bf16 convert (wq scaled) ----------------
__global__ __launch_bounds__(256) void conv_w4(const float* __restrict__ w0, const float* __restrict__ w1,
                                               const float* __restrict__ w2, const float* __restrict__ w3,
                                               short* __restrict__ dst, float s0) {
    int idx = (blockIdx.x * 256 + threadIdx.x) * 4;
    int wi = idx >> 18;
    int off = idx & 262143;
    const float* src = (wi == 0) ? w0 : (wi == 1) ? w1 : (wi == 2) ? w2 : w3;
    float sc = (wi == 0) ? s0 : 1.0f;
    float4v v = *reinterpret_cast<const float4v*>(src + off);
    short4v o;
    o[0] = f2bf(v[0] * sc); o[1] = f2bf(v[1] * sc);
    o[2] = f2bf(v[2] * sc); o[3] = f2bf(v[3] * sc);
    *reinterpret_cast<short4v*>(dst + idx) = o;
}

// bqk[0:512] = bq*s ; bqk[512:1024] = bk
__global__ __launch_bounds__(256) void prep_bias(const float* __restrict__ bq, const float* __restrict__ bk,
                                                 float* __restrict__ bqk, float s) {
    int i = blockIdx.x * 256 + threadIdx.x;
    bqk[i] = (i < 512) ? bq[i] * s : bk[i - 512];
}

// ---------------- GroupNorm stats: one block per (b,g) ----------------
__global__ __launch_bounds__(256) void gn_stats(const float* __restrict__ x, float* __restrict__ stats) {
    int bg = blockIdx.x;
    const float* p = x + (size_t)bg * (16 * 4096);
    float s = 0.f, ss = 0.f;
    for (int i = threadIdx.x * 4; i < 65536; i += 1024) {
        float4v q = *reinterpret_cast<const float4v*>(p + i);
        s  += q[0] + q[1] + q[2] + q[3];
        ss += q[0]*q[0] + q[1]*q[1] + q[2]*q[2] + q[3]*q[3];
    }
    #pragma unroll
    for (int off = 32; off >= 1; off >>= 1) {
        s  += __shfl_xor(s, off);
        ss += __shfl_xor(ss, off);
    }
    __shared__ float rs[8];
    int w = threadIdx.x >> 6, lane = threadIdx.x & 63;
    if (lane == 0) { rs[w] = s; rs[4 + w] = ss; }
    __syncthreads();
    if (threadIdx.x == 0) {
        float S1 = rs[0] + rs[1] + rs[2] + rs[3];
        float S2 = rs[4] + rs[5] + rs[6] + rs[7];
        float mean = S1 * (1.f / 65536.f);
        float var  = S2 * (1.f / 65536.f) - mean * mean;
        stats[bg * 2]     = mean;
        stats[bg * 2 + 1] = rsqrtf(var + 1e-6f);
    }
}

// ---------------- GN apply + transpose: x[b][c][n] -> hT[b][n][c] (bf16) ----------------
__global__ __launch_bounds__(256) void gn_apply_t(const float* __restrict__ x, const float* __restrict__ stats,
                                                  const float* __restrict__ scale, const float* __restrict__ bias,
                                                  short* __restrict__ hT) {
    __shared__ float t[64][65];
    int n0 = blockIdx.x * 64, c0 = blockIdx.y * 64, b = blockIdx.z;
    const float* xb = x + (size_t)b * 512 * 4096;
    int col = threadIdx.x & 63, rb = threadIdx.x >> 6;
    #pragma unroll
    for (int r = 0; r < 16; ++r) {
        int cl = rb + r * 4;
        int c = c0 + cl;
        int g = c >> 4;
        float mean = stats[(b * 32 + g) * 2];
        float rstd = stats[(b * 32 + g) * 2 + 1];
        float v = xb[(size_t)c * 4096 + n0 + col];
        t[col][cl] = (v - mean) * rstd * scale[c] + bias[c];
    }
    __syncthreads();
    short* hb = hT + (size_t)b * 4096 * 512;
    #pragma unroll
    for (int r = 0; r < 16; ++r) {
        int nl = rb + r * 4;
        hb[(size_t)(n0 + nl) * 512 + c0 + col] = f2bf(t[nl][col]);
    }
}

// ================ 256x256 NT GEMM, BK=64, 1024 threads = 16 waves ================
// C[M][N] = A[M][K]*B[N][K]^T, bf16 in, fp32 acc, bf16 out. 16 waves (4M x 4N),
// wave tile 64x64 (acc = 64 VGPR, ~90 live total). LDS 2 x 64KB double-buffered.
// 4 waves/SIMD: within each phase the SIMD interleaves one wave's ds_reads with
// another's MFMAs (m114 TLP mechanism) — no exotic scheduling needed.
// Proven-conflict-free 128B-row layout, (kk*16)^((r&7)<<4) swizzle, inverse-
// swizzled gload source. 2-barrier counted-vmcnt loop (race-free).
__global__ __launch_bounds__(1024, 1) void gemm1k(
    const short* __restrict__ A, int zdiv, long sAb1, long sAb2, int lda,
    const short* __restrict__ B, long sBb1, long sBb2, int ldb,
    short* __restrict__ C, long sCb1, long sCb2, int ldc,
    int K)
{
    __shared__ __align__(16) char lds[131072];  // 2 buf x (A 32KB + B 32KB)

    const int tid = threadIdx.x;
    int bx = blockIdx.x, by = blockIdx.y;
    swz_xy(bx, by);
    const int bm = bx * 256, bn = by * 256;
    const int zb = blockIdx.z / zdiv, zs = blockIdx.z % zdiv;

    const short* Ab = A + (size_t)zb * sAb1 + (size_t)zs * sAb2;
    const short* Bb = B + (size_t)zb * sBb1 + (size_t)zs * sBb2;

    const int w = tid >> 6, lane = tid & 63;
    const int wm = w >> 2, wn = w & 3;          // 4M x 4N
    const int l15 = lane & 15, l4 = lane >> 4;

    // staging: A = 2048 chunks of 16B (2/thread), B same.
    long srcA[2], srcB[2]; int dstA[2], dstB[2];
    #pragma unroll
    for (int i = 0; i < 2; ++i) {
        int ch = i * 1024 + tid;
        int r = ch >> 3, c = ch & 7;
        srcA[i] = (long)(bm + r) * lda + ((c ^ (r & 7)) << 3);
        dstA[i] = r * 128 + c * 16;
        srcB[i] = (long)(bn + r) * ldb + ((c ^ (r & 7)) << 3);
        dstB[i] = 32768 + r * 128 + c * 16;
    }

    auto stage = [&](int buf, long kt) {
        char* l = lds + buf * 65536;
        gload_lds16(Ab + srcA[0] + kt, l + dstA[0]);
        gload_lds16(Ab + srcA[1] + kt, l + dstA[1]);
        gload_lds16(Bb + srcB[0] + kt, l + dstB[0]);
        gload_lds16(Bb + srcB[1] + kt, l + dstB[1]);
    };

    f32x4 acc[4][4] = {};
    const int nk = K >> 6;

    stage(0, 0);
    int cur = 0;
    for (int t = 0; t < nk; ++t) {
        if (t + 1 < nk) {
            stage(cur ^ 1, (long)(t + 1) << 6);
            wait_vm<4>();          // tile t landed; t+1's 4 loads stay in flight
        } else {
            wait_vm<0>();
        }
        phase_barrier();

        const char* l = lds + cur * 65536;
        #pragma unroll
        for (int ks = 0; ks < 2; ++ks) {
            const int kk16 = (ks * 4 + l4) * 16;
            short8 bfv[4];
            #pragma unroll
            for (int n = 0; n < 4; ++n) {
                int r = wn * 64 + n * 16 + l15;
                bfv[n] = *reinterpret_cast<const short8*>(l + 32768 + r * 128 + (kk16 ^ ((r & 7) << 4)));
            }
            #pragma unroll
            for (int m = 0; m < 4; ++m) {
                int r = wm * 64 + m * 16 + l15;
                short8 af = *reinterpret_cast<const short8*>(l + r * 128 + (kk16 ^ ((r & 7) << 4)));
                #pragma unroll
                for (int n = 0; n < 4; ++n)
                    acc[m][n] = __builtin_amdgcn_mfma_f32_16x16x32_bf16(af, bfv[n], acc[m][n], 0, 0, 0);
            }
        }
        asm volatile("" ::: "memory");
        __builtin_amdgcn_s_barrier();   // all waves done reading buf before next stage overwrites
        cur ^= 1;
    }

    short* Cb = C + (size_t)zb * sCb1 + (size_t)zs * sCb2;
    #pragma unroll
    for (int m = 0; m < 4; ++m) {
        #pragma unroll
        for (int r = 0; r < 4; ++r) {
            int row = bm + wm * 64 + m * 16 + l4 * 4 + r;
            #pragma unroll
            for (int n = 0; n < 4; ++n) {
                int col = bn + wn * 64 + n * 16 + l15;
                Cb[(size_t)row * ldc + col] = f2bf(acc[m][n][r]);
            }
        }
    }
}

// ================ 2-phase NT GEMM (512 thr) for QK projection ================
template<int BMT, int BNT, int WM, int WN>
__global__ __launch_bounds__(512) void gemm_nt3(
    const short* __restrict__ A, int zdiv, long sAb1, long sAb2, int lda,
    const short* __restrict__ B, long sBb1, long sBb2, int ldb,
    void* __restrict__ Cv, long sCb1, long sCb2, int ldc,
    int K,
    const float* __restrict__ bias, int bias_mode,
    const float* __restrict__ res, long sResb,
    int c_fp32)
{
    constexpr int BUFB = (BMT + BNT) * 128;
    constexpr int ALPT = BMT / 64;
    constexpr int BLPT = BNT / 64;
    constexpr int LPT  = ALPT + BLPT;
    constexpr int MF   = BMT / WM / 16;
    constexpr int NF   = BNT / WN / 16;
    __shared__ __align__(16) char lds[2 * BUFB];

    const int tid = threadIdx.x;
    int bx = blockIdx.x, by = blockIdx.y;
    swz_xy(bx, by);
    const int bm = bx * BMT;
    const int bn = by * BNT;
    const int bz = blockIdx.z;
    const int zb = bz / zdiv, zs = bz % zdiv;

    const short* Ab = A + (size_t)zb * sAb1 + (size_t)zs * sAb2;
    const short* Bb = B + (size_t)zb * sBb1 + (size_t)zs * sBb2;

    const int w = tid >> 6;
    const int lane = tid & 63;
    const int wm = w / WN, wn = w % WN;
    const int wr = wm * (BMT / WM);
    const int wc = wn * (BNT / WN);

    f32x4 acc[MF][NF] = {};
    const int nk = K >> 6;

    auto stage = [&](int buf, int kt) {
        char* la = lds + buf * BUFB;
        char* lb = la + BMT * 128;
        #pragma unroll
        for (int i = 0; i < ALPT; ++i) {
            int ch = i * 512 + tid;
            int r = ch >> 3, c = ch & 7;
            gload_lds16(Ab + (size_t)(bm + r) * lda + kt + ((c ^ (r & 7)) << 3), la + ch * 16);
        }
        #pragma unroll
        for (int i = 0; i < BLPT; ++i) {
            int ch = i * 512 + tid;
            int r = ch >> 3, c = ch & 7;
            gload_lds16(Bb + (size_t)(bn + r) * ldb + kt + ((c ^ (r & 7)) << 3), lb + ch * 16);
        }
    };

    stage(0, 0);
    int cur = 0;
    for (int t = 0; t < nk; ++t) {
        if (t + 1 < nk) {
            stage(cur ^ 1, (t + 1) << 6);
            wait_vm<6>();
        } else {
            wait_vm<0>();
        }
        phase_barrier();

        const char* la = lds + cur * BUFB;
        const char* lb = la + BMT * 128;
        #pragma unroll
        for (int ks = 0; ks < 2; ++ks) {
            const int kb = ks * 64 + (lane >> 4) * 16;
            short8 af[MF], bfv[NF];
            #pragma unroll
            for (int m = 0; m < MF; ++m) {
                int r = wr + m * 16 + (lane & 15);
                af[m] = *reinterpret_cast<const short8*>(la + r * 128 + (kb ^ ((r & 7) << 4)));
            }
            #pragma unroll
            for (int n = 0; n < NF; ++n) {
                int r = wc + n * 16 + (lane & 15);
                bfv[n] = *reinterpret_cast<const short8*>(lb + r * 128 + (kb ^ ((r & 7) << 4)));
            }
            #pragma unroll
            for (int m = 0; m < MF; ++m)
                #pragma unroll
                for (int n = 0; n < NF; ++n)
                    acc[m][n] = __builtin_amdgcn_mfma_f32_16x16x32_bf16(af[m], bfv[n], acc[m][n], 0, 0, 0);
        }
        asm volatile("" ::: "memory");
        __builtin_amdgcn_s_barrier();
        cur ^= 1;
    }

    const int row0 = (lane >> 4) * 4;
    const int col0 = lane & 15;
    short* Cb16 = (short*)Cv + (size_t)zb * sCb1 + (size_t)zs * sCb2;
    float* Cf32 = (float*)Cv + (size_t)zb * sCb1 + (size_t)zs * sCb2;
    const float* resb = res ? res + (size_t)zb * sResb : nullptr;

    #pragma unroll
    for (int m = 0; m < MF; ++m) {
        #pragma unroll
        for (int r = 0; r < 4; ++r) {
            int row = bm + wr + m * 16 + row0 + r;
            float bvr = (bias_mode == 1) ? bias[row] : 0.0f;
            #pragma unroll
            for (int n = 0; n < NF; ++n) {
                int col = bn + wc + n * 16 + col0;
                float v = acc[m][n][r];
                if (bias_mode == 1) v += bvr;
                else if (bias_mode == 2) v += bias[col];
                size_t idx = (size_t)row * ldc + col;
                if (c_fp32) {
                    if (resb) v += resb[idx];
                    Cf32[idx] = v;
                } else {
                    Cb16[idx] = f2bf(v);
                }
            }
        }
    }
}

// ---------------- small NT GEMM (4 waves, 128 x BNT), counted-vmcnt pipeline ----------------
template<int BNT>
__global__ __launch_bounds__(256) void gemm_nt2(
    const short* __restrict__ A, long sAb, int lda,
    const short* __restrict__ B, long sBb, int ldb,
    void* __restrict__ Cv, long sCb, int ldc,
    int K,
    const float* __restrict__ bias, int bias_mode,
    const float* __restrict__ res, long sResb,
    int c_fp32)
{
    constexpr int BMT = 128;
    constexpr int NF  = BNT / 32;
    constexpr int BUF = (BMT + BNT) * 128;
    constexpr int ALPT = (BMT * 8) / 256;
    constexpr int BLPT = (BNT * 8) / 256;
    constexpr int LPT  = ALPT + BLPT;
    __shared__ __align__(16) char lds[2 * BUF];

    const int tid = threadIdx.x;
    int bx = blockIdx.x, by = blockIdx.y;
    swz_xy(bx, by);
    const int bm = bx * BMT;
    const int bn = by * BNT;
    const int bz = blockIdx.z;

    const short* Ab = A + (size_t)bz * sAb;
    const short* Bb = B + (size_t)bz * sBb;

    const int w = tid >> 6;
    const int lane = tid & 63;
    const int wr = (w >> 1) * 64;
    const int wc = (w & 1) * (BNT / 2);

    f32x4 acc[4][NF] = {};
    const int nk = K >> 6;

    auto stage = [&](int buf, int kt) {
        char* la = lds + buf * BUF;
        char* lb = la + BMT * 128;
        #pragma unroll
        for (int i = 0; i < ALPT; ++i) {
            int ch = i * 256 + tid;
            int r = ch >> 3, c = ch & 7;
            gload_lds16(Ab + (size_t)(bm + r) * lda + kt + ((c ^ (r & 7)) << 3), la + ch * 16);
        }
        #pragma unroll
        for (int i = 0; i < BLPT; ++i) {
            int ch = i * 256 + tid;
            int r = ch >> 3, c = ch & 7;
            gload_lds16(Bb + (size_t)(bn + r) * ldb + kt + ((c ^ (r & 7)) << 3), lb + ch * 16);
        }
    };

    stage(0, 0);
    int cur = 0;
    for (int t = 0; t < nk; ++t) {
        if (t + 1 < nk) {
            stage(cur ^ 1, (t + 1) << 6);
            wait_vm<6>();
        } else {
            wait_vm<0>();
        }
        phase_barrier();

        const char* la = lds + cur * BUF;
        const char* lb = la + BMT * 128;
        #pragma unroll
        for (int ks = 0; ks < 2; ++ks) {
            const int kb = ks * 64 + (lane >> 4) * 16;
            short8 af[4], bfv[NF];
            #pragma unroll
            for (int m = 0; m < 4; ++m) {
                int r = wr + m * 16 + (lane & 15);
                af[m] = *reinterpret_cast<const short8*>(la + r * 128 + (kb ^ ((r & 7) << 4)));
            }
            #pragma unroll
            for (int n = 0; n < NF; ++n) {
                int r = wc + n * 16 + (lane & 15);
                bfv[n] = *reinterpret_cast<const short8*>(lb + r * 128 + (kb ^ ((r & 7) << 4)));
            }
            #pragma unroll
            for (int m = 0; m < 4; ++m)
                #pragma unroll
                for (int n = 0; n < NF; ++n)
                    acc[m][n] = __builtin_amdgcn_mfma_f32_16x16x32_bf16(af[m], bfv[n], acc[m][n], 0, 0, 0);
        }
        asm volatile("" ::: "memory");
        __builtin_amdgcn_s_barrier();
        cur ^= 1;
    }

    const int row0 = (lane >> 4) * 4;
    const int col0 = lane & 15;
    short* Cb16 = (short*)Cv + (size_t)bz * sCb;
    float* Cf32 = (float*)Cv + (size_t)bz * sCb;
    const float* resb = res ? res + (size_t)bz * sResb : nullptr;

    #pragma unroll
    for (int m = 0; m < 4; ++m) {
        #pragma unroll
        for (int r = 0; r < 4; ++r) {
            int row = bm + wr + m * 16 + row0 + r;
            float bvr = (bias_mode == 1) ? bias[row] : 0.0f;
            #pragma unroll
            for (int n = 0; n < NF; ++n) {
                int col = bn + wc + n * 16 + col0;
                float v = acc[m][n][r];
                if (bias_mode == 1) v += bvr;
                else if (bias_mode == 2) v += bias[col];
                size_t idx = (size_t)row * ldc + col;
                if (c_fp32) {
                    if (resb) v += resb[idx];
                    Cf32[idx] = v;
                } else {
                    Cb16[idx] = f2bf(v);
                }
            }
        }
    }
}

// ---------------- row softmax in-place on bf16 [4096] rows (both batches) ----------------
__global__ __launch_bounds__(256) void softmax_rows(short* __restrict__ S) {
    const int N = 4096;
    short* p = S + (size_t)blockIdx.x * N + threadIdx.x * 16;
    short8 r0 = *reinterpret_cast<short8*>(p);
    short8 r1 = *reinterpret_cast<short8*>(p + 8);
    float v[16];
    #pragma unroll
    for (int i = 0; i < 8; ++i) { v[i] = bf2f(r0[i]); v[8 + i] = bf2f(r1[i]); }
    float mx = v[0];
    #pragma unroll
    for (int i = 1; i < 16; ++i) mx = fmaxf(mx, v[i]);
    #pragma unroll
    for (int off = 32; off >= 1; off >>= 1) mx = fmaxf(mx, __shfl_xor(mx, off));
    __shared__ float red[8];
    int w = threadIdx.x >> 6, lane = threadIdx.x & 63;
    if (lane == 0) red[w] = mx;
    __syncthreads();
    mx = fmaxf(fmaxf(red[0], red[1]), fmaxf(red[2], red[3]));
    float s = 0.f;
    #pragma unroll
    for (int i = 0; i < 16; ++i) { v[i] = __expf(v[i] - mx); s += v[i]; }
    #pragma unroll
    for (int off = 32; off >= 1; off >>= 1) s += __shfl_xor(s, off);
    if (lane == 0) red[4 + w] = s;
    __syncthreads();
    s = (red[4] + red[5]) + (red[6] + red[7]);
    float inv = 1.0f / s;
    #pragma unroll
    for (int i = 0; i < 8; ++i) { r0[i] = f2bf(v[i] * inv); r1[i] = f2bf(v[8 + i] * inv); }
    *reinterpret_cast<short8*>(p) = r0;
    *reinterpret_cast<short8*>(p + 8) = r1;
}

// ---------------- split-K reduce: OT_bf16 = sum of 4 bf16 partials (grid.y = batch) ----------------
__global__ __launch_bounds__(256) void reduce4b(const short* __restrict__ p, short* __restrict__ o) {
    const long NN = 4096L * 512L;
    const short* pb = p + (size_t)blockIdx.y * 4 * NN;
    short* ob = o + (size_t)blockIdx.y * NN;
    long i = (blockIdx.x * 256 + threadIdx.x) * 8L;
    short8 a = *reinterpret_cast<const short8*>(pb + i);
    short8 b = *reinterpret_cast<const short8*>(pb + NN + i);
    short8 c = *reinterpret_cast<const short8*>(pb + 2 * NN + i);
    short8 d = *reinterpret_cast<const short8*>(pb + 3 * NN + i);
    short8 r;
    #pragma unroll
    for (int j = 0; j < 8; ++j)
        r[j] = f2bf((bf2f(a[j]) + bf2f(b[j])) + (bf2f(c[j]) + bf2f(d[j])));
    *reinterpret_cast<short8*>(ob + i) = r;
}

extern "C" void kernel_launch(void* const* d_in, const int* in_sizes, int n_in,
                              void* d_out, int out_size, void* d_ws, size_t ws_size,
                              hipStream_t stream) {
    (void)in_sizes; (void)n_in; (void)out_size; (void)ws_size;
    const float* x        = (const float*)d_in[0];
    const float* gn_scale = (const float*)d_in[1];
    const float* gn_bias  = (const float*)d_in[2];
    const float* wq = (const float*)d_in[3];
    const float* bq = (const float*)d_in[4];
    const float* wk = (const float*)d_in[5];
    const float* bk = (const float*)d_in[6];
    const float* wv = (const float*)d_in[7];
    const float* bv = (const float*)d_in[8];
    const float* wp = (const float*)d_in[9];
    const float* bp = (const float*)d_in[10];

    char* ws = (char*)d_ws;
    const size_t MB = 1024 * 1024;
    short* hT   = (short*)(ws + 0);         // [2][4096][512] bf16     (8MB)
    short* QKT  = (short*)(ws + 8   * MB);  // [2][4096][1024] bf16   (16MB)
    short* V    = (short*)(ws + 24  * MB);  // [2][512][4096] bf16     (8MB)
    short* OT   = (short*)(ws + 32  * MB);  // [2][4096][512] bf16     (8MB)
    short* S    = (short*)(ws + 40  * MB);  // [2][4096][4096] bf16   (64MB)
    short* part = (short*)(ws + 104 * MB);  // [2][4][4096][512] bf16 (32MB)
    short* wB   = (short*)(ws + 168 * MB);  // wq,wk,wv,wp bf16        (2MB)
    float* stats= (float*)(ws + 170 * MB);  // 128 f
    float* bqk  = (float*)(ws + 170 * MB + 4096);  // 1024 f

    const long NC   = 4096L * 512L;    // 2M
    const long CN   = 512L * 4096L;
    const long QKNC = 4096L * 1024L;   // 4M
    const long SNN  = 4096L * 4096L;   // 16M
    const float attn_scale = 0.044194173824159216f;  // 512^-0.5

    conv_w4<<<1024, 256, 0, stream>>>(wq, wk, wv, wp, wB, attn_scale);
    prep_bias<<<4, 256, 0, stream>>>(bq, bk, bqk, attn_scale);

    gn_stats<<<64, 256, 0, stream>>>(x, stats);
    gn_apply_t<<<dim3(64, 8, 2), 256, 0, stream>>>(x, stats, gn_scale, gn_bias, hT);

    // QK projection (merged): QKT[b][n][0:512]=Q*s, [512:1024]=K
    gemm_nt3<128, 256, 2, 4><<<dim3(32, 4, 2), 512, 0, stream>>>(
        hT, 1, NC, 0, 512, wB, 0, 0, 512, QKT, QKNC, 0, 1024, 512, bqk, 2, nullptr, 0, 0);
    // V[b][c][n]
    gemm_nt2<64><<<dim3(4, 64, 2), 256, 0, stream>>>(
        wB + 524288, 0, 512, hT, NC, 512, V, CN, 4096, 512, bv, 1, nullptr, 0, 0);

    // S[b][i][j] = sum_c Q[i][c] K[j][c]  (scale pre-folded), both batches
    gemm1k<<<dim3(16, 16, 2), 1024, 0, stream>>>(
        QKT, 1, QKNC, 0, 1024, QKT + 512, QKNC, 0, 1024, S, SNN, 0, 4096, 512);
    softmax_rows<<<8192, 256, 0, stream>>>(S);
    // PV split-K=4, both batches: z = batch*4 + slice, K=1024 per slice, bf16 partials
    gemm1k<<<dim3(16, 2, 8), 1024, 0, stream>>>(
        S, 4, SNN, 1024, 4096, V, CN, 1024, 4096, part, 4L * NC, NC, 512, 1024);
    reduce4b<<<dim3(1024, 2), 256, 0, stream>>>(part, OT);

    // out[b][c][n] = wp . o + bp + x
    gemm_nt2<64><<<dim3(4, 64, 2), 256, 0, stream>>>(
        wB + 786432, 0, 512, OT, NC, 512, d_out, CN, 4096, 512, bp, 1, x, CN, 1);
}